// Round 3
// baseline (436.552 us; speedup 1.0000x reference)
//
#include <hip/hip_runtime.h>
#include <hip/hip_fp16.h>

#define CV_B 8
#define CV_C 128
#define CV_H 128
#define CV_W 240
#define CV_V 48
#define PLANE (CV_H * CV_W)

#define NCP 4                  // c-pairs per stage (= 8 channels)
#define NSTAGE 16              // 16 stages x 8 c = 128 c
#define GUARDF 12              // guard vec4s (= 48 half2 words) left of each R row
#define LROW 60                // L row: 60 vec4 (240 half2 c-pair words)
#define RROW (GUARDF + LROW)   // 72 vec4 = 1152 B per R row

// LDS element is a TRUE LLVM vector (ext_vector_type): float4/int4 are
// structs -> SROA splits their LDS accesses into 4x ds_read_b32 (16B lane
// stride -> 8-way bank conflict, was 2.36e7 cycles). ext_vector loads stay
// single ds_read_b128, conflict-free (verified: conflicts dropped to 8192).
typedef unsigned int u32x4 __attribute__((ext_vector_type(4)));

static __device__ __forceinline__ __half2 bc_h2(unsigned v) {
    return __builtin_bit_cast(__half2, v);
}
static __device__ __forceinline__ unsigned bc_u(__half2 v) {
    return __builtin_bit_cast(unsigned, v);
}

// Occupancy is the lever now: at NCP=8 the 33.8KB LDS capped residency at
// 4 blocks/CU (16 waves, 35% occ) and no pipe exceeded 25% busy -- pure
// latency exposure. NCP=4 halves LDS to 16.9KB -> 8 blocks/CU -> 32 waves.
__global__ __launch_bounds__(256, 8) void cost_volume_kernel(
        const float* __restrict__ Lf, const float* __restrict__ Rf,
        float* __restrict__ out)
{
    // ping-pong stage buffers: 2 x 4 cp x (60 + 72) vec4 = 16,896 B
    __shared__ u32x4 sL[2][NCP][LROW];
    __shared__ u32x4 sR[2][NCP][RROW];

    const int t  = threadIdx.x;
    const int y  = blockIdx.x;
    const int b  = blockIdx.y;
    const int wv = t >> 6;              // wave id: i-group AND staging role
    const int u  = t & 63;              // lane: x-group (x0 = 4u), u<60 active
    const bool act = (u < 60);
    const int x0 = 4 * u;

    const float* Lrow = Lf + (size_t)(b * CV_C) * PLANE + y * CV_W;
    const float* Rrow = Rf + (size_t)(b * CV_C) * PLANE + y * CV_W;

    // staging roles: waves 0,1 stage L (2 c-pairs each); waves 2,3 stage R
    const int side = wv >> 1;
    const int a0   = (wv & 1) * 2;
    const float* Srow = side ? Rrow : Lrow;

    // ---- zero R guards once (both buffers; commits never write f < GUARDF) ----
    for (int idx = t; idx < 2 * NCP * GUARDF; idx += 256) {
        const int bi = idx / (NCP * GUARDF);
        const int rm = idx % (NCP * GUARDF);
        u32x4 z; z.x = 0u; z.y = 0u; z.z = 0u; z.w = 0u;
        sR[bi][rm / GUARDF][rm % GUARDF] = z;
    }

    float4 f0[2], f1[2];

    // ---- prologue: load + commit stage 0 into buffer 0 ----
    if (act) {
#pragma unroll
        for (int q = 0; q < 2; ++q) {
            const float* p = Srow + (size_t)(2 * (a0 + q)) * PLANE + x0;
            f0[q] = *(const float4*)p;            // row c   (960 B contiguous/inst)
            f1[q] = *(const float4*)(p + PLANE);  // row c+1
        }
#pragma unroll
        for (int q = 0; q < 2; ++q) {
            u32x4 w;
            w.x = bc_u(__floats2half2_rn(f0[q].x, f1[q].x));
            w.y = bc_u(__floats2half2_rn(f0[q].y, f1[q].y));
            w.z = bc_u(__floats2half2_rn(f0[q].z, f1[q].z));
            w.w = bc_u(__floats2half2_rn(f0[q].w, f1[q].w));
            if (side) sR[0][a0 + q][GUARDF + u] = w;   // ds_write_b128
            else      sL[0][a0 + q][u]          = w;
        }
    }
    __syncthreads();

    // ---- accumulators: thread tile = 4 x  X  12 i  (i = 12*wv + r) ----
    __half2 acc[4][12];
#pragma unroll
    for (int xx = 0; xx < 4; ++xx)
#pragma unroll
        for (int r = 0; r < 12; ++r) acc[xx][r] = __floats2half2_rn(0.f, 0.f);

    // R window start (vec4 units): word index 4*rbase = 48 + (4u - 12wv - 12)
    const int rbase = GUARDF - 3 - 3 * wv + u;   // >= 0, window guard-covered

    for (int s = 0; s < NSTAGE; ++s) {
        const int P = s & 1;
        const bool pf = (s + 1 < NSTAGE);

        // 1) issue next stage's global loads (in flight through compute)
        if (pf && act) {
#pragma unroll
            for (int q = 0; q < 2; ++q) {
                const float* p = Srow + (size_t)(8 * (s + 1) + 2 * (a0 + q)) * PLANE + x0;
                f0[q] = *(const float4*)p;
                f1[q] = *(const float4*)(p + PLANE);
            }
        }

        // 2) compute stage s from buf[P]: channels 8s .. 8s+7
        if (act) {
            const u32x4 (*__restrict__ sLp)[LROW] = sL[P];
            const u32x4 (*__restrict__ sRp)[RROW] = sR[P];
#pragma unroll
            for (int cp = 0; cp < NCP; ++cp) {
                const u32x4 lvv = sLp[cp][u];            // ds_read_b128
                u32x4 rv[4];
#pragma unroll
                for (int kk = 0; kk < 4; ++kk)
                    rv[kk] = sRp[cp][rbase + kk];        // ds_read_b128 x4

                __half2 lw[4];
                lw[0] = bc_h2(lvv.x); lw[1] = bc_h2(lvv.y);
                lw[2] = bc_h2(lvv.z); lw[3] = bc_h2(lvv.w);
                __half2 rw[16];
#pragma unroll
                for (int kk = 0; kk < 4; ++kk) {
                    rw[4 * kk + 0] = bc_h2(rv[kk].x);
                    rw[4 * kk + 1] = bc_h2(rv[kk].y);
                    rw[4 * kk + 2] = bc_h2(rv[kk].z);
                    rw[4 * kk + 3] = bc_h2(rv[kk].w);
                }
#pragma unroll
                for (int r = 0; r < 12; ++r) {
#pragma unroll
                    for (int xx = 0; xx < 4; ++xx) {
                        const int m = xx + 12 - r;        // window idx, 1..15
                        acc[xx][r] = __hfma2(lw[xx], rw[m], acc[xx][r]);
                    }
                }
            }
        }

        // 3) convert + commit stage s+1 into the other buffer (readers of
        //    buf[P^1] finished at the barrier ending stage s-1 -> race-free)
        if (pf && act) {
#pragma unroll
            for (int q = 0; q < 2; ++q) {
                u32x4 w;
                w.x = bc_u(__floats2half2_rn(f0[q].x, f1[q].x));
                w.y = bc_u(__floats2half2_rn(f0[q].y, f1[q].y));
                w.z = bc_u(__floats2half2_rn(f0[q].z, f1[q].z));
                w.w = bc_u(__floats2half2_rn(f0[q].w, f1[q].w));
                if (side) sR[P ^ 1][a0 + q][GUARDF + u] = w;
                else      sL[P ^ 1][a0 + q][u]          = w;
            }
        }
        if (pf) __syncthreads();   // single barrier per stage
    }

    // ---- epilogue: fold half2 (lo=even c, hi=odd c), scale, coalesced store ----
    if (act) {
#pragma unroll
        for (int r = 0; r < 12; ++r) {
            const int i = 12 * wv + r;
            float4 o;
            o.x = (__low2float(acc[0][r]) + __high2float(acc[0][r])) * (1.f / 128.f);
            o.y = (__low2float(acc[1][r]) + __high2float(acc[1][r])) * (1.f / 128.f);
            o.z = (__low2float(acc[2][r]) + __high2float(acc[2][r])) * (1.f / 128.f);
            o.w = (__low2float(acc[3][r]) + __high2float(acc[3][r])) * (1.f / 128.f);
            *(float4*)&out[(((size_t)b * CV_V + i) * CV_H + y) * CV_W + x0] = o;
        }
    }
}

extern "C" void kernel_launch(void* const* d_in, const int* in_sizes, int n_in,
                              void* d_out, int out_size, void* d_ws, size_t ws_size,
                              hipStream_t stream)
{
    const float* Lf = (const float*)d_in[0];
    const float* Rf = (const float*)d_in[1];
    float* o = (float*)d_out;
    dim3 grid(CV_H, CV_B);   // one block per (y, b): 1024 blocks x 256 thr
    dim3 block(256);
    hipLaunchKernelGGL(cost_volume_kernel, grid, block, 0, stream, Lf, Rf, o);
}

// Round 4
// 340.560 us; speedup vs baseline: 1.2819x; 1.2819x over previous
//
#include <hip/hip_runtime.h>
#include <hip/hip_fp16.h>

#define CV_B 8
#define CV_C 128
#define CV_H 128
#define CV_W 240
#define CV_V 48
#define PLANE (CV_H * CV_W)

#define NCP 4                  // c-pairs per stage (= 8 channels)
#define NSTAGE 16              // 16 stages x 8 c = 128 c
#define GUARDF 12              // guard vec4s (= 48 half2 words) left of each R row
#define LROW 60                // L row: 60 vec4 (240 half2 c-pair words)
#define RROW (GUARDF + LROW)   // 72 vec4 = 1152 B per R row

// LDS element is a TRUE LLVM vector (ext_vector_type): float4/int4 are
// structs -> SROA splits their LDS accesses into 4x ds_read_b32 (16B lane
// stride -> 8-way bank conflict, was 2.36e7 cycles). ext_vector loads stay
// single ds_read_b128, conflict-free (verified: conflicts dropped to 8192).
typedef unsigned int u32x4 __attribute__((ext_vector_type(4)));

static __device__ __forceinline__ __half2 bc_h2(unsigned v) {
    return __builtin_bit_cast(__half2, v);
}
static __device__ __forceinline__ unsigned bc_u(__half2 v) {
    return __builtin_bit_cast(unsigned, v);
}

// Occupancy lever, take 2. R3's __launch_bounds__(256,8) capped VGPRs at 32
// (< the 48-reg accumulator alone) -> acc spilled to scratch: WRITE_SIZE
// 46MB -> 548MB, dur 110 -> 268us. Live state needs ~75 VGPRs, so the
// feasible point is 6 waves/SIMD (cap = 512/6 = 85 regs, no spill):
// 24 waves/CU vs R2's 16, LDS 6 x 16.9KB = 101KB < 160KB.
__global__ __launch_bounds__(256, 6) void cost_volume_kernel(
        const float* __restrict__ Lf, const float* __restrict__ Rf,
        float* __restrict__ out)
{
    // ping-pong stage buffers: 2 x 4 cp x (60 + 72) vec4 = 16,896 B
    __shared__ u32x4 sL[2][NCP][LROW];
    __shared__ u32x4 sR[2][NCP][RROW];

    const int t  = threadIdx.x;
    const int y  = blockIdx.x;
    const int b  = blockIdx.y;
    const int wv = t >> 6;              // wave id: i-group AND staging role
    const int u  = t & 63;              // lane: x-group (x0 = 4u), u<60 active
    const bool act = (u < 60);
    const int x0 = 4 * u;

    const float* Lrow = Lf + (size_t)(b * CV_C) * PLANE + y * CV_W;
    const float* Rrow = Rf + (size_t)(b * CV_C) * PLANE + y * CV_W;

    // staging roles: waves 0,1 stage L (2 c-pairs each); waves 2,3 stage R
    const int side = wv >> 1;
    const int a0   = (wv & 1) * 2;
    const float* Srow = side ? Rrow : Lrow;

    // ---- zero R guards once (both buffers; commits never write f < GUARDF) ----
    for (int idx = t; idx < 2 * NCP * GUARDF; idx += 256) {
        const int bi = idx / (NCP * GUARDF);
        const int rm = idx % (NCP * GUARDF);
        u32x4 z; z.x = 0u; z.y = 0u; z.z = 0u; z.w = 0u;
        sR[bi][rm / GUARDF][rm % GUARDF] = z;
    }

    float4 f0[2], f1[2];

    // ---- prologue: load + commit stage 0 into buffer 0 ----
    if (act) {
#pragma unroll
        for (int q = 0; q < 2; ++q) {
            const float* p = Srow + (size_t)(2 * (a0 + q)) * PLANE + x0;
            f0[q] = *(const float4*)p;            // row c   (960 B contiguous/inst)
            f1[q] = *(const float4*)(p + PLANE);  // row c+1
        }
#pragma unroll
        for (int q = 0; q < 2; ++q) {
            u32x4 w;
            w.x = bc_u(__floats2half2_rn(f0[q].x, f1[q].x));
            w.y = bc_u(__floats2half2_rn(f0[q].y, f1[q].y));
            w.z = bc_u(__floats2half2_rn(f0[q].z, f1[q].z));
            w.w = bc_u(__floats2half2_rn(f0[q].w, f1[q].w));
            if (side) sR[0][a0 + q][GUARDF + u] = w;   // ds_write_b128
            else      sL[0][a0 + q][u]          = w;
        }
    }
    __syncthreads();

    // ---- accumulators: thread tile = 4 x  X  12 i  (i = 12*wv + r) ----
    __half2 acc[4][12];
#pragma unroll
    for (int xx = 0; xx < 4; ++xx)
#pragma unroll
        for (int r = 0; r < 12; ++r) acc[xx][r] = __floats2half2_rn(0.f, 0.f);

    // R window start (vec4 units): word index 4*rbase = 48 + (4u - 12wv - 12)
    const int rbase = GUARDF - 3 - 3 * wv + u;   // >= 0, window guard-covered

    for (int s = 0; s < NSTAGE; ++s) {
        const int P = s & 1;
        const bool pf = (s + 1 < NSTAGE);

        // 1) issue next stage's global loads (in flight through compute)
        if (pf && act) {
#pragma unroll
            for (int q = 0; q < 2; ++q) {
                const float* p = Srow + (size_t)(8 * (s + 1) + 2 * (a0 + q)) * PLANE + x0;
                f0[q] = *(const float4*)p;
                f1[q] = *(const float4*)(p + PLANE);
            }
        }

        // 2) compute stage s from buf[P]: channels 8s .. 8s+7
        if (act) {
            const u32x4 (*__restrict__ sLp)[LROW] = sL[P];
            const u32x4 (*__restrict__ sRp)[RROW] = sR[P];
#pragma unroll
            for (int cp = 0; cp < NCP; ++cp) {
                const u32x4 lvv = sLp[cp][u];            // ds_read_b128
                u32x4 rv[4];
#pragma unroll
                for (int kk = 0; kk < 4; ++kk)
                    rv[kk] = sRp[cp][rbase + kk];        // ds_read_b128 x4

                __half2 lw[4];
                lw[0] = bc_h2(lvv.x); lw[1] = bc_h2(lvv.y);
                lw[2] = bc_h2(lvv.z); lw[3] = bc_h2(lvv.w);
                __half2 rw[16];
#pragma unroll
                for (int kk = 0; kk < 4; ++kk) {
                    rw[4 * kk + 0] = bc_h2(rv[kk].x);
                    rw[4 * kk + 1] = bc_h2(rv[kk].y);
                    rw[4 * kk + 2] = bc_h2(rv[kk].z);
                    rw[4 * kk + 3] = bc_h2(rv[kk].w);
                }
#pragma unroll
                for (int r = 0; r < 12; ++r) {
#pragma unroll
                    for (int xx = 0; xx < 4; ++xx) {
                        const int m = xx + 12 - r;        // window idx, 1..15
                        acc[xx][r] = __hfma2(lw[xx], rw[m], acc[xx][r]);
                    }
                }
            }
        }

        // 3) convert + commit stage s+1 into the other buffer (readers of
        //    buf[P^1] finished at the barrier ending stage s-1 -> race-free)
        if (pf && act) {
#pragma unroll
            for (int q = 0; q < 2; ++q) {
                u32x4 w;
                w.x = bc_u(__floats2half2_rn(f0[q].x, f1[q].x));
                w.y = bc_u(__floats2half2_rn(f0[q].y, f1[q].y));
                w.z = bc_u(__floats2half2_rn(f0[q].z, f1[q].z));
                w.w = bc_u(__floats2half2_rn(f0[q].w, f1[q].w));
                if (side) sR[P ^ 1][a0 + q][GUARDF + u] = w;
                else      sL[P ^ 1][a0 + q][u]          = w;
            }
        }
        if (pf) __syncthreads();   // single barrier per stage
    }

    // ---- epilogue: fold half2 (lo=even c, hi=odd c), scale, coalesced store ----
    if (act) {
#pragma unroll
        for (int r = 0; r < 12; ++r) {
            const int i = 12 * wv + r;
            float4 o;
            o.x = (__low2float(acc[0][r]) + __high2float(acc[0][r])) * (1.f / 128.f);
            o.y = (__low2float(acc[1][r]) + __high2float(acc[1][r])) * (1.f / 128.f);
            o.z = (__low2float(acc[2][r]) + __high2float(acc[2][r])) * (1.f / 128.f);
            o.w = (__low2float(acc[3][r]) + __high2float(acc[3][r])) * (1.f / 128.f);
            *(float4*)&out[(((size_t)b * CV_V + i) * CV_H + y) * CV_W + x0] = o;
        }
    }
}

extern "C" void kernel_launch(void* const* d_in, const int* in_sizes, int n_in,
                              void* d_out, int out_size, void* d_ws, size_t ws_size,
                              hipStream_t stream)
{
    const float* Lf = (const float*)d_in[0];
    const float* Rf = (const float*)d_in[1];
    float* o = (float*)d_out;
    dim3 grid(CV_H, CV_B);   // one block per (y, b): 1024 blocks x 256 thr
    dim3 block(256);
    hipLaunchKernelGGL(cost_volume_kernel, grid, block, 0, stream, Lf, Rf, o);
}

// Round 5
// 278.350 us; speedup vs baseline: 1.5684x; 1.2235x over previous
//
#include <hip/hip_runtime.h>
#include <hip/hip_fp16.h>

#define CV_B 8
#define CV_C 128
#define CV_H 128
#define CV_W 240
#define CV_V 48
#define PLANE (CV_H * CV_W)

#define NCP 4                  // c-pairs per stage (= 8 channels)
#define NSTAGE 16              // 16 stages x 8 c = 128 c
#define GUARDF 12              // guard vec4s (= 48 half2 words) left of each R row
#define LROW 60                // L row: 60 vec4 (240 half2 c-pair words)
#define RROW (GUARDF + LROW)   // 72 vec4 = 1152 B per R row

// LDS element is a TRUE LLVM vector (ext_vector_type): float4/int4 are
// structs -> SROA splits their LDS accesses into 4x ds_read_b32 (16B lane
// stride -> 8-way bank conflict, was 2.36e7 cycles). ext_vector loads stay
// single ds_read_b128, conflict-free (verified: conflicts dropped to 8192).
typedef unsigned int u32x4 __attribute__((ext_vector_type(4)));

static __device__ __forceinline__ __half2 bc_h2(unsigned v) {
    return __builtin_bit_cast(__half2, v);
}
static __device__ __forceinline__ unsigned bc_u(__half2 v) {
    return __builtin_bit_cast(unsigned, v);
}

// Register-budget lessons (measured): launch_bounds(256,8) -> 32 VGPRs,
// launch_bounds(256,6) -> 40 VGPRs -- BOTH below the 48-reg accumulator, so
// the allocator spills acc to scratch (WRITE_SIZE 46MB -> 548/322MB).
// (256,4) is the proven-non-spilling bound (R2: 64 VGPRs, WRITE 46MB).
// With NCP=4 the LDS is 16.9KB so LDS no longer caps residency at 4 blocks;
// at ~75-80 live VGPRs hardware occupancy reaches 6 waves/SIMD (24/CU).
__global__ __launch_bounds__(256, 4) void cost_volume_kernel(
        const float* __restrict__ Lf, const float* __restrict__ Rf,
        float* __restrict__ out)
{
    // ping-pong stage buffers: 2 x 4 cp x (60 + 72) vec4 = 16,896 B
    __shared__ u32x4 sL[2][NCP][LROW];
    __shared__ u32x4 sR[2][NCP][RROW];

    const int t  = threadIdx.x;
    const int y  = blockIdx.x;
    const int b  = blockIdx.y;
    const int wv = t >> 6;              // wave id: i-group AND staging role
    const int u  = t & 63;              // lane: x-group (x0 = 4u), u<60 active
    const bool act = (u < 60);
    const int x0 = 4 * u;

    const float* Lrow = Lf + (size_t)(b * CV_C) * PLANE + y * CV_W;
    const float* Rrow = Rf + (size_t)(b * CV_C) * PLANE + y * CV_W;

    // staging roles: waves 0,1 stage L (2 c-pairs each); waves 2,3 stage R
    const int side = wv >> 1;
    const int a0   = (wv & 1) * 2;
    const float* Srow = side ? Rrow : Lrow;

    // ---- zero R guards once (both buffers; commits never write f < GUARDF) ----
    for (int idx = t; idx < 2 * NCP * GUARDF; idx += 256) {
        const int bi = idx / (NCP * GUARDF);
        const int rm = idx % (NCP * GUARDF);
        u32x4 z; z.x = 0u; z.y = 0u; z.z = 0u; z.w = 0u;
        sR[bi][rm / GUARDF][rm % GUARDF] = z;
    }

    float4 f0[2], f1[2];

    // ---- prologue: load + commit stage 0 into buffer 0 ----
    if (act) {
#pragma unroll
        for (int q = 0; q < 2; ++q) {
            const float* p = Srow + (size_t)(2 * (a0 + q)) * PLANE + x0;
            f0[q] = *(const float4*)p;            // row c   (960 B contiguous/inst)
            f1[q] = *(const float4*)(p + PLANE);  // row c+1
        }
#pragma unroll
        for (int q = 0; q < 2; ++q) {
            u32x4 w;
            w.x = bc_u(__floats2half2_rn(f0[q].x, f1[q].x));
            w.y = bc_u(__floats2half2_rn(f0[q].y, f1[q].y));
            w.z = bc_u(__floats2half2_rn(f0[q].z, f1[q].z));
            w.w = bc_u(__floats2half2_rn(f0[q].w, f1[q].w));
            if (side) sR[0][a0 + q][GUARDF + u] = w;   // ds_write_b128
            else      sL[0][a0 + q][u]          = w;
        }
    }
    __syncthreads();

    // ---- accumulators: thread tile = 4 x  X  12 i  (i = 12*wv + r) ----
    __half2 acc[4][12];
#pragma unroll
    for (int xx = 0; xx < 4; ++xx)
#pragma unroll
        for (int r = 0; r < 12; ++r) acc[xx][r] = __floats2half2_rn(0.f, 0.f);

    // R window start (vec4 units): word index 4*rbase = 48 + (4u - 12wv - 12)
    const int rbase = GUARDF - 3 - 3 * wv + u;   // >= 0, window guard-covered

    for (int s = 0; s < NSTAGE; ++s) {
        const int P = s & 1;
        const bool pf = (s + 1 < NSTAGE);

        // 1) issue next stage's global loads (in flight through compute)
        if (pf && act) {
#pragma unroll
            for (int q = 0; q < 2; ++q) {
                const float* p = Srow + (size_t)(8 * (s + 1) + 2 * (a0 + q)) * PLANE + x0;
                f0[q] = *(const float4*)p;
                f1[q] = *(const float4*)(p + PLANE);
            }
        }

        // 2) compute stage s from buf[P]: channels 8s .. 8s+7
        if (act) {
            const u32x4 (*__restrict__ sLp)[LROW] = sL[P];
            const u32x4 (*__restrict__ sRp)[RROW] = sR[P];
#pragma unroll
            for (int cp = 0; cp < NCP; ++cp) {
                const u32x4 lvv = sLp[cp][u];            // ds_read_b128
                u32x4 rv[4];
#pragma unroll
                for (int kk = 0; kk < 4; ++kk)
                    rv[kk] = sRp[cp][rbase + kk];        // ds_read_b128 x4

                __half2 lw[4];
                lw[0] = bc_h2(lvv.x); lw[1] = bc_h2(lvv.y);
                lw[2] = bc_h2(lvv.z); lw[3] = bc_h2(lvv.w);
                __half2 rw[16];
#pragma unroll
                for (int kk = 0; kk < 4; ++kk) {
                    rw[4 * kk + 0] = bc_h2(rv[kk].x);
                    rw[4 * kk + 1] = bc_h2(rv[kk].y);
                    rw[4 * kk + 2] = bc_h2(rv[kk].z);
                    rw[4 * kk + 3] = bc_h2(rv[kk].w);
                }
#pragma unroll
                for (int r = 0; r < 12; ++r) {
#pragma unroll
                    for (int xx = 0; xx < 4; ++xx) {
                        const int m = xx + 12 - r;        // window idx, 1..15
                        acc[xx][r] = __hfma2(lw[xx], rw[m], acc[xx][r]);
                    }
                }
            }
        }

        // 3) convert + commit stage s+1 into the other buffer (readers of
        //    buf[P^1] finished at the barrier ending stage s-1 -> race-free)
        if (pf && act) {
#pragma unroll
            for (int q = 0; q < 2; ++q) {
                u32x4 w;
                w.x = bc_u(__floats2half2_rn(f0[q].x, f1[q].x));
                w.y = bc_u(__floats2half2_rn(f0[q].y, f1[q].y));
                w.z = bc_u(__floats2half2_rn(f0[q].z, f1[q].z));
                w.w = bc_u(__floats2half2_rn(f0[q].w, f1[q].w));
                if (side) sR[P ^ 1][a0 + q][GUARDF + u] = w;
                else      sL[P ^ 1][a0 + q][u]          = w;
            }
        }
        if (pf) __syncthreads();   // single barrier per stage
    }

    // ---- epilogue: fold half2 (lo=even c, hi=odd c), scale, coalesced store ----
    if (act) {
#pragma unroll
        for (int r = 0; r < 12; ++r) {
            const int i = 12 * wv + r;
            float4 o;
            o.x = (__low2float(acc[0][r]) + __high2float(acc[0][r])) * (1.f / 128.f);
            o.y = (__low2float(acc[1][r]) + __high2float(acc[1][r])) * (1.f / 128.f);
            o.z = (__low2float(acc[2][r]) + __high2float(acc[2][r])) * (1.f / 128.f);
            o.w = (__low2float(acc[3][r]) + __high2float(acc[3][r])) * (1.f / 128.f);
            *(float4*)&out[(((size_t)b * CV_V + i) * CV_H + y) * CV_W + x0] = o;
        }
    }
}

extern "C" void kernel_launch(void* const* d_in, const int* in_sizes, int n_in,
                              void* d_out, int out_size, void* d_ws, size_t ws_size,
                              hipStream_t stream)
{
    const float* Lf = (const float*)d_in[0];
    const float* Rf = (const float*)d_in[1];
    float* o = (float*)d_out;
    dim3 grid(CV_H, CV_B);   // one block per (y, b): 1024 blocks x 256 thr
    dim3 block(256);
    hipLaunchKernelGGL(cost_volume_kernel, grid, block, 0, stream, Lf, Rf, o);
}